// Round 10
// baseline (91.095 us; speedup 1.0000x reference)
//
#include <hip/hip_runtime.h>
#include <hip/hip_bf16.h>

#define T_DIM 800
#define B_DIM 32
#define V_DIM 1024
#define S_DIM 100
#define L2E  1.4426950408889634f
#define LN2  0.6931471805599453f

#define NB1  1600                /* K1 blocks: 16 rows each (25600 rows total) */
#define EOFF 4096                /* E starts at ws + EOFF floats (16 KB) */
#define EROW 128                 /* padded E row: 104 used slots */

// ws layout (32-bit slots):
// [0]                  : uint counter (zeroed by hipMemsetAsync each call)
// [1 .. 1+NB1)         : float partial sums (smoothing reduction)
// [1+NB1 .. 1+NB1+32)  : float per-batch nll
// [EOFF ..)            : E[32][800][128] emission matrix (13.1 MB)

#define SBAR __builtin_amdgcn_sched_barrier(0)

__device__ __forceinline__ float dpp_shr1_f(float x) {
    return __int_as_float(__builtin_amdgcn_update_dpp(
        0, __float_as_int(x), 0x138, 0xF, 0xF, false));
}
__device__ __forceinline__ int dpp_shr1_i(int x) {
    return __builtin_amdgcn_update_dpp(0, x, 0x138, 0xF, 0xF, false);
}
__device__ __forceinline__ float rl50(float x) {
    return __int_as_float(__builtin_amdgcn_readlane(__float_as_int(x), 50));
}

// ========== K1: fused smoothing-reduction + LDS-gathered E build ==========
extern "C" __global__ void __launch_bounds__(256)
ctc_prep(const float* __restrict__ lp,
         const int* __restrict__ tgt,
         float* __restrict__ ws)
{
    __shared__ float rowbuf[2][V_DIM];
    __shared__ float red[4];
    float* E = ws + EOFF;
    float* partials = ws + 1;
    const int bid = blockIdx.x;
    const int tid = threadIdx.x;
    const int b  = bid / 50;            // 50 blocks per batch
    const int t0 = (bid - b * 50) * 16;
    const int* tg = tgt + b * S_DIM;

    float s = 0.0f;
    #pragma unroll 1
    for (int i = 0; i < 16; ++i) {
        const int t = t0 + i;
        const float4 v = ((const float4*)(lp + ((size_t)t * B_DIM + b) * V_DIM))[tid];
        s += (v.x + v.y) + (v.z + v.w);
        ((float4*)rowbuf[i & 1])[tid] = v;
        __syncthreads();
        if (tid < 64) {
            const float* rb = rowbuf[i & 1];
            const int m = tid;
            float a, c;
            if (m <= 49) {                       // slots 2m,2m+1 = labels 2m,2m+1
                int2 t2 = ((const int2*)tg)[m];
                a = __builtin_amdgcn_exp2f(rb[t2.x] * L2E);
                c = __builtin_amdgcn_exp2f(rb[t2.y] * L2E);
            } else if (m == 50) {                // slots 100,101 = blank
                float ebv = __builtin_amdgcn_exp2f(rb[0] * L2E);
                a = ebv; c = ebv;
            } else {                             // slots 102..127 = dead
                a = 0.0f; c = 0.0f;
            }
            ((float2*)(E + ((size_t)b * 800 + t) * EROW))[m] = make_float2(a, c);
        }
    }
    for (int off = 32; off; off >>= 1) s += __shfl_down(s, off, 64);
    if ((tid & 63) == 0) red[tid >> 6] = s;
    __syncthreads();
    if (tid == 0) partials[bid] = (red[0] + red[1]) + (red[2] + red[3]);
}

// ========== K2: recursion (1 wave/block, 8-bank / 32-step pinned prefetch) ==========
extern "C" __global__ void __launch_bounds__(64)
ctc_rec(const int* __restrict__ tgt,
        const int* __restrict__ ilen,
        const int* __restrict__ tlen,
        float* __restrict__ ws,
        float* __restrict__ out)
{
    unsigned int* cnt = (unsigned int*)ws;
    float* partials = ws + 1;
    float* nlls = ws + 1 + NB1;
    const int b = blockIdx.x;
    const int l = threadIdx.x;
    const float* E = ws + EOFF + (size_t)b * 800 * EROW;
    const int* tg = tgt + b * S_DIM;
    const int len = ilen[b];
    const int tl  = tlen[b];
    const int steps = len - 1;          // t = 1..len-1 ; len in [400,800]

    // skip-transition flags (lane l owns extended states 4l..4l+3)
    float cs1f = 0, cs3f = 0;
    if (l <= 49) {
        int v1 = tg[2 * l];
        int vp = (l >= 1) ? tg[2 * l - 1] : -1;
        cs1f = (v1 != vp) ? 1.0f : 0.0f;
        int v3 = tg[2 * l + 1];
        cs3f = (v3 != v1) ? 1.0f : 0.0f;
    }

    // t=0 init from E row 0: lane l's float2 = slots (2l, 2l+1); blank = lane50.x
    float p0 = 0, p1 = 0, p2 = 0, p3 = 0;
    float qv = 0, sff = 0, sfg = 0;
    int   el = 0, eLp = 0;
    {
        float2 q0 = ((const float2*)E)[l];
        float eb0 = rl50(q0.x);
        p0 = (l == 0) ? eb0  : 0.0f;
        p1 = (l == 0) ? q0.x : 0.0f;
    }

    // 8-bank register prefetch of 4-step groups (group g = steps 1+4g .. 4+4g).
    // sched_barrier(0) after each PREFG pins the loads at issue position —
    // R9's VGPR=60 proved the compiler otherwise sinks them to their uses.
    float2 eq[8][4];
#define PREFG(bk, G) do { \
    int tb_ = 1 + 4 * (G); \
    _Pragma("unroll") \
    for (int i_ = 0; i_ < 4; ++i_) { \
        int tc_ = tb_ + i_; tc_ = (tc_ > T_DIM - 1) ? (T_DIM - 1) : tc_; \
        eq[bk][i_] = ((const float2*)(E + (size_t)tc_ * EROW))[l]; \
    } \
} while (0)

// renorm lane max to [1,2); 2-level dead-lane exponent adoption; scale factors
// from POST-adoption left exponent (validated R6..R9 protocol).
#define BD do { \
    float mz_ = fmaxf(fmaxf(p0, p1), fmaxf(p2, p3)); \
    int dead_ = (mz_ == 0.0f) ? 1 : 0; \
    int er_ = (int)((__float_as_uint(mz_) >> 23) & 255u); \
    unsigned fld_ = dead_ ? 127u : (unsigned)(254 - er_); \
    float sc_ = __uint_as_float(fld_ << 23); \
    p0 *= sc_; p1 *= sc_; p2 *= sc_; p3 *= sc_; \
    el += dead_ ? 0 : (er_ - 127); \
    int e1s_ = dpp_shr1_i(el); \
    int elA_ = dead_ ? e1s_ : el; \
    int e2s_ = dpp_shr1_i(elA_); \
    int elB_ = dead_ ? e2s_ : el; \
    int e3s_ = dpp_shr1_i(elB_); \
    int d1_ = e3s_ - elB_; d1_ = d1_ < -120 ? -120 : (d1_ > 120 ? 120 : d1_); \
    int d2_ = eLp  - elB_; d2_ = d2_ < -120 ? -120 : (d2_ > 120 ? 120 : d2_); \
    sfg = (l == 0) ? 0.0f : __uint_as_float((unsigned)(d1_ + 127) << 23); \
    sff = (l == 0) ? 0.0f : __uint_as_float((unsigned)(d2_ + 127) << 23); \
    el = elB_; eLp = e3s_; \
} while (0)

#define ST(SF, Q, EBS) do { \
    float h3_ = qv * (SF); \
    float vown_ = fmaf(cs3f, p1, p2 + p3); \
    float n3_ = vown_ * (Q).y; \
    float n0_ = (p0 + h3_) * (EBS); \
    float n1_ = fmaf(cs1f, h3_, p0 + p1) * (Q).x; \
    float n2_ = (p1 + p2) * (EBS); \
    qv = dpp_shr1_f(n3_); \
    p0 = n0_; p1 = n1_; p2 = n2_; p3 = n3_; \
} while (0)

#define GRP(bk) do { \
    BD; \
    ST(sff, eq[bk][0], rl50(eq[bk][0].x)); \
    ST(sfg, eq[bk][1], rl50(eq[bk][1].x)); \
    ST(sfg, eq[bk][2], rl50(eq[bk][2].x)); \
    ST(sfg, eq[bk][3], rl50(eq[bk][3].x)); \
} while (0)

#define GRPT(bk, BASE) do { \
    if ((BASE) < nst) { \
        BD; \
        ST(sff, eq[bk][0], rl50(eq[bk][0].x)); \
        if ((BASE) + 1 < nst) ST(sfg, eq[bk][1], rl50(eq[bk][1].x)); \
        if ((BASE) + 2 < nst) ST(sfg, eq[bk][2], rl50(eq[bk][2].x)); \
        if ((BASE) + 3 < nst) ST(sfg, eq[bk][3], rl50(eq[bk][3].x)); \
    } \
} while (0)

    PREFG(0, 0); PREFG(1, 1); PREFG(2, 2); PREFG(3, 3);
    PREFG(4, 4); PREFG(5, 5); PREFG(6, 6); PREFG(7, 7);
    SBAR;
    const int nsb = steps >> 5;         // full 32-step superblocks (>= 12)
    for (int s = 0; s < nsb; ++s) {
        GRP(0); PREFG(0, 8 * s + 8);  SBAR;
        GRP(1); PREFG(1, 8 * s + 9);  SBAR;
        GRP(2); PREFG(2, 8 * s + 10); SBAR;
        GRP(3); PREFG(3, 8 * s + 11); SBAR;
        GRP(4); PREFG(4, 8 * s + 12); SBAR;
        GRP(5); PREFG(5, 8 * s + 13); SBAR;
        GRP(6); PREFG(6, 8 * s + 14); SBAR;
        GRP(7); PREFG(7, 8 * s + 15); SBAR;
    }
    {
        const int nst = steps & 31;     // 0..31 remaining steps
        GRPT(0, 0);  GRPT(1, 4);  GRPT(2, 8);  GRPT(3, 12);
        GRPT(4, 16); GRPT(5, 20); GRPT(6, 24); GRPT(7, 28);
    }

    // extract alpha[2*tl] and alpha[2*tl-1]  (log2 domain via p, el)
    int idx = 2 * tl;
    int lanehi = idx >> 2, rhi = idx & 3;
    int lanelo = (idx - 1) >> 2, rlo = (idx - 1) & 3;
    float q0 = __shfl(p0, lanehi, 64), q1 = __shfl(p1, lanehi, 64);
    float q2 = __shfl(p2, lanehi, 64), q3 = __shfl(p3, lanehi, 64);
    int   eh = __shfl(el, lanehi, 64);
    float ph = (rhi == 0) ? q0 : (rhi == 1) ? q1 : (rhi == 2) ? q2 : q3;
    float g0 = __shfl(p0, lanelo, 64), g1 = __shfl(p1, lanelo, 64);
    float g2 = __shfl(p2, lanelo, 64), g3 = __shfl(p3, lanelo, 64);
    int   eo = __shfl(el, lanelo, 64);
    float pl = (rlo == 0) ? g0 : (rlo == 1) ? g1 : (rlo == 2) ? g2 : g3;
    float vhi = (ph > 0.0f) ? __builtin_amdgcn_logf(ph) + (float)eh : -3.0e9f;
    float vlo = (pl > 0.0f) ? __builtin_amdgcn_logf(pl) + (float)eo : -3.0e9f;
    float m = fmaxf(vhi, vlo);
    float d = fminf(vhi, vlo) - m;
    float ll2 = m + __builtin_amdgcn_logf(1.0f + __builtin_amdgcn_exp2f(d));
    float nll = -ll2 * LN2;
    if (!(nll < 1e9f)) nll = 0.0f;      // zero_infinity (NaN-safe)

    int last = 0;
    if (l == 0) {
        nlls[b] = nll;
        __threadfence();
        unsigned old = __hip_atomic_fetch_add(cnt, 1u, __ATOMIC_ACQ_REL,
                                              __HIP_MEMORY_SCOPE_AGENT);
        last = (old == B_DIM - 1) ? 1 : 0;
    }
    last = __shfl(last, 0, 64);
    if (last) {
        // deterministic final combine (partials written by K1, stream-ordered)
        float ps = 0.0f;
        for (int i = l; i < NB1; i += 64) ps += partials[i];
        for (int off = 32; off; off >>= 1) ps += __shfl_down(ps, off, 64);
        float cs = 0.0f;
        if (l < B_DIM) cs = nlls[l] / (float)tlen[l];
        for (int off = 32; off; off >>= 1) cs += __shfl_down(cs, off, 64);
        if (l == 0) {
            float smooth = -ps / (float)((long long)T_DIM * B_DIM * V_DIM);
            float ctc = cs / (float)B_DIM;
            out[0] = 0.9f * ctc + 0.1f * smooth;
        }
    }
}

extern "C" void kernel_launch(void* const* d_in, const int* in_sizes, int n_in,
                              void* d_out, int out_size, void* d_ws, size_t ws_size,
                              hipStream_t stream) {
    const float* lp  = (const float*)d_in[0];
    const int* tgt   = (const int*)d_in[1];
    const int* ilen  = (const int*)d_in[2];
    const int* tlen  = (const int*)d_in[3];
    float* out = (float*)d_out;
    float* ws  = (float*)d_ws;
    hipMemsetAsync(d_ws, 0, 4, stream);
    ctc_prep<<<NB1, 256, 0, stream>>>(lp, tgt, ws);
    ctc_rec<<<B_DIM, 64, 0, stream>>>(tgt, ilen, tlen, ws, out);
}

// Round 14
// 75.970 us; speedup vs baseline: 1.1991x; 1.1991x over previous
//
#include <hip/hip_runtime.h>
#include <hip/hip_bf16.h>

#define T_DIM 800
#define B_DIM 32
#define V_DIM 1024
#define S_DIM 100
#define L2E  1.4426950408889634f
#define LN2  0.6931471805599453f

#define NB1  1600                /* K1 blocks: 16 rows each */
#define EOFF 4096                /* E starts at ws + EOFF floats (16 KB) */
#define EROW 128                 /* padded E row: 104 used slots (512 B) */
#define BROWS 801                /* per-batch row stride (row 800 = overrun pad) */

// ws layout (32-bit slots):
// [0]                  : uint counter (zeroed by hipMemsetAsync each call)
// [1 .. 1+NB1)         : float partial sums (smoothing reduction)
// [1+NB1 .. 1+NB1+32)  : float per-batch nll
// [EOFF ..)            : E[32][801][128] emission matrix (13.1 MB)

__device__ __forceinline__ float dpp_shr1_f(float x) {
    return __int_as_float(__builtin_amdgcn_update_dpp(
        0, __float_as_int(x), 0x138, 0xF, 0xF, false));
}
__device__ __forceinline__ int dpp_shr1_i(int x) {
    return __builtin_amdgcn_update_dpp(0, x, 0x138, 0xF, 0xF, false);
}
__device__ __forceinline__ float rl50(float x) {
    return __int_as_float(__builtin_amdgcn_readlane(__float_as_int(x), 50));
}
__device__ __forceinline__ void gl16(const float* g, float* lds_dst) {
    __builtin_amdgcn_global_load_lds(
        (const __attribute__((address_space(1))) unsigned int*)g,
        (__attribute__((address_space(3))) unsigned int*)lds_dst,
        16, 0, 0);
}

// ========== K1: fused smoothing-reduction + LDS-gathered E build ==========
extern "C" __global__ void __launch_bounds__(256)
ctc_prep(const float* __restrict__ lp,
         const int* __restrict__ tgt,
         float* __restrict__ ws)
{
    __shared__ float rowbuf[2][V_DIM];
    __shared__ float red[4];
    float* E = ws + EOFF;
    float* partials = ws + 1;
    const int bid = blockIdx.x;
    const int tid = threadIdx.x;
    const int b  = bid / 50;            // 50 blocks per batch
    const int t0 = (bid - b * 50) * 16;
    const int* tg = tgt + b * S_DIM;

    float s = 0.0f;
    #pragma unroll 1
    for (int i = 0; i < 16; ++i) {
        const int t = t0 + i;
        const float4 v = ((const float4*)(lp + ((size_t)t * B_DIM + b) * V_DIM))[tid];
        s += (v.x + v.y) + (v.z + v.w);
        ((float4*)rowbuf[i & 1])[tid] = v;
        __syncthreads();
        if (tid < 64) {
            const float* rb = rowbuf[i & 1];
            const int m = tid;
            float a, c;
            if (m <= 49) {                       // slots 2m,2m+1 = labels 2m,2m+1
                int2 t2 = ((const int2*)tg)[m];
                a = __builtin_amdgcn_exp2f(rb[t2.x] * L2E);
                c = __builtin_amdgcn_exp2f(rb[t2.y] * L2E);
            } else if (m == 50) {                // slots 100,101 = blank
                float ebv = __builtin_amdgcn_exp2f(rb[0] * L2E);
                a = ebv; c = ebv;
            } else {                             // slots 102..127 = dead
                a = 0.0f; c = 0.0f;
            }
            ((float2*)(E + ((size_t)b * BROWS + t) * EROW))[m] = make_float2(a, c);
        }
    }
    for (int off = 32; off; off >>= 1) s += __shfl_down(s, off, 64);
    if ((tid & 63) == 0) red[tid >> 6] = s;
    __syncthreads();
    if (tid == 0) partials[bid] = (red[0] + red[1]) + (red[2] + red[3]);
}

// ========== K2: recursion — global_load_lds double-buffer, vmcnt(0) only ==========
// R11-R13 post-mortem: register-destination asm loads are unauditable (regalloc
// copies read in-flight load dests). Here staging is global_load_lds into two
// DISTINCT __shared__ arrays (no register dest at all); consumers are ds_reads
// (memory ops), so the "memory"-clobbered vmcnt(0) at each superblock boundary
// legitimately orders them. Depth-1 pipeline: stage SB+1 while computing SB
// (~1100cy VALU > load latency); no vmcnt counting anywhere.
extern "C" __global__ void __launch_bounds__(64)
ctc_rec(const int* __restrict__ tgt,
        const int* __restrict__ ilen,
        const int* __restrict__ tlen,
        float* __restrict__ ws,
        float* __restrict__ out)
{
    __shared__ float bufA[32 * EROW];   // 16 KB
    __shared__ float bufB[32 * EROW];   // 16 KB
    unsigned int* cnt = (unsigned int*)ws;
    float* partials = ws + 1;
    float* nlls = ws + 1 + NB1;
    const int b = blockIdx.x;
    const int l = threadIdx.x;
    const float* E = ws + EOFF + (size_t)b * BROWS * EROW;
    const int* tg = tgt + b * S_DIM;
    const int len = ilen[b];
    const int tl  = tlen[b];
    const int steps = len - 1;          // t = 1..len-1 ; len in [400,800]

    // skip-transition flags (lane l owns extended states 4l..4l+3)
    float cs1f = 0, cs3f = 0;
    if (l <= 49) {
        int v1 = tg[2 * l];
        int vp = (l >= 1) ? tg[2 * l - 1] : -1;
        cs1f = (v1 != vp) ? 1.0f : 0.0f;
        int v3 = tg[2 * l + 1];
        cs3f = (v3 != v1) ? 1.0f : 0.0f;
    }

    // t=0 init from E row 0
    float p0 = 0, p1 = 0, p2 = 0, p3 = 0;
    float qv = 0, sff = 0, sfg = 0;
    int   el = 0, eLp = 0;
    {
        float2 q0 = ((const float2*)E)[l];
        float eb0 = rl50(q0.x);
        p0 = (l == 0) ? eb0  : 0.0f;
        p1 = (l == 0) ? q0.x : 0.0f;
    }

    // 1-group-ahead LDS->reg banks (named vars, static only)
    float2 ga0, ga1, ga2, ga3, gb0, gb1, gb2, gb3;

#define STAGE(BUF, SB) do { \
    const int tb_ = 1 + 32 * (SB); \
    _Pragma("unroll") \
    for (int g_ = 0; g_ < 16; ++g_) { \
        gl16(E + (size_t)(tb_ + 2 * g_) * EROW + 4 * l, &BUF[g_ * 256]); \
    } \
} while (0)

#define WAIT0 do { \
    asm volatile("s_waitcnt vmcnt(0)" ::: "memory"); \
    __builtin_amdgcn_sched_barrier(0); \
} while (0)

#define PREF_(BUF, G, R0, R1, R2, R3) do { \
    const float2* bp_ = (const float2*)(BUF); \
    R0 = bp_[(4 * (G) + 0) * 64 + l]; \
    R1 = bp_[(4 * (G) + 1) * 64 + l]; \
    R2 = bp_[(4 * (G) + 2) * 64 + l]; \
    R3 = bp_[(4 * (G) + 3) * 64 + l]; \
} while (0)

// renorm lane max to [1,2); 2-level dead-lane exponent adoption; scale factors
// from POST-adoption left exponent (validated R6..R10 protocol).
#define BD do { \
    float mz_ = fmaxf(fmaxf(p0, p1), fmaxf(p2, p3)); \
    int dead_ = (mz_ == 0.0f) ? 1 : 0; \
    int er_ = (int)((__float_as_uint(mz_) >> 23) & 255u); \
    unsigned fld_ = dead_ ? 127u : (unsigned)(254 - er_); \
    float sc_ = __uint_as_float(fld_ << 23); \
    p0 *= sc_; p1 *= sc_; p2 *= sc_; p3 *= sc_; \
    el += dead_ ? 0 : (er_ - 127); \
    int e1s_ = dpp_shr1_i(el); \
    int elA_ = dead_ ? e1s_ : el; \
    int e2s_ = dpp_shr1_i(elA_); \
    int elB_ = dead_ ? e2s_ : el; \
    int e3s_ = dpp_shr1_i(elB_); \
    int d1_ = e3s_ - elB_; d1_ = d1_ < -120 ? -120 : (d1_ > 120 ? 120 : d1_); \
    int d2_ = eLp  - elB_; d2_ = d2_ < -120 ? -120 : (d2_ > 120 ? 120 : d2_); \
    sfg = (l == 0) ? 0.0f : __uint_as_float((unsigned)(d1_ + 127) << 23); \
    sff = (l == 0) ? 0.0f : __uint_as_float((unsigned)(d2_ + 127) << 23); \
    el = elB_; eLp = e3s_; \
} while (0)

#define ST(SF, Q, EBS) do { \
    float h3_ = qv * (SF); \
    float vown_ = fmaf(cs3f, p1, p2 + p3); \
    float n3_ = vown_ * (Q).y; \
    float n0_ = (p0 + h3_) * (EBS); \
    float n1_ = fmaf(cs1f, h3_, p0 + p1) * (Q).x; \
    float n2_ = (p1 + p2) * (EBS); \
    qv = dpp_shr1_f(n3_); \
    p0 = n0_; p1 = n1_; p2 = n2_; p3 = n3_; \
} while (0)

#define GRP_(R0, R1, R2, R3) do { \
    BD; \
    ST(sff, R0, rl50(R0.x)); \
    ST(sfg, R1, rl50(R1.x)); \
    ST(sfg, R2, rl50(R2.x)); \
    ST(sfg, R3, rl50(R3.x)); \
} while (0)

#define GRPT_(R0, R1, R2, R3, BASE) do { \
    if ((BASE) < nst) { \
        BD; \
        ST(sff, R0, rl50(R0.x)); \
        if ((BASE) + 1 < nst) ST(sfg, R1, rl50(R1.x)); \
        if ((BASE) + 2 < nst) ST(sfg, R2, rl50(R2.x)); \
        if ((BASE) + 3 < nst) ST(sfg, R3, rl50(R3.x)); \
    } \
} while (0)

#define CONS_FULL(BUF) do { \
    PREF_(BUF, 0, ga0, ga1, ga2, ga3); \
    PREF_(BUF, 1, gb0, gb1, gb2, gb3); GRP_(ga0, ga1, ga2, ga3); \
    PREF_(BUF, 2, ga0, ga1, ga2, ga3); GRP_(gb0, gb1, gb2, gb3); \
    PREF_(BUF, 3, gb0, gb1, gb2, gb3); GRP_(ga0, ga1, ga2, ga3); \
    PREF_(BUF, 4, ga0, ga1, ga2, ga3); GRP_(gb0, gb1, gb2, gb3); \
    PREF_(BUF, 5, gb0, gb1, gb2, gb3); GRP_(ga0, ga1, ga2, ga3); \
    PREF_(BUF, 6, ga0, ga1, ga2, ga3); GRP_(gb0, gb1, gb2, gb3); \
    PREF_(BUF, 7, gb0, gb1, gb2, gb3); GRP_(ga0, ga1, ga2, ga3); \
    GRP_(gb0, gb1, gb2, gb3); \
} while (0)

#define CONS_TAIL(BUF) do { \
    PREF_(BUF, 0, ga0, ga1, ga2, ga3); \
    PREF_(BUF, 1, gb0, gb1, gb2, gb3); GRPT_(ga0, ga1, ga2, ga3, 0); \
    PREF_(BUF, 2, ga0, ga1, ga2, ga3); GRPT_(gb0, gb1, gb2, gb3, 4); \
    PREF_(BUF, 3, gb0, gb1, gb2, gb3); GRPT_(ga0, ga1, ga2, ga3, 8); \
    PREF_(BUF, 4, ga0, ga1, ga2, ga3); GRPT_(gb0, gb1, gb2, gb3, 12); \
    PREF_(BUF, 5, gb0, gb1, gb2, gb3); GRPT_(ga0, ga1, ga2, ga3, 16); \
    PREF_(BUF, 6, ga0, ga1, ga2, ga3); GRPT_(gb0, gb1, gb2, gb3, 20); \
    PREF_(BUF, 7, gb0, gb1, gb2, gb3); GRPT_(ga0, ga1, ga2, ga3, 24); \
    GRPT_(gb0, gb1, gb2, gb3, 28); \
} while (0)

    const int nfull = steps >> 5;       // full 32-step superblocks (>= 12)
    const int nst   = steps & 31;       // tail steps (0..31)

    STAGE(bufA, 0);
    WAIT0;                               // SB0 landed (also drains init loads)
    int sb = 0;
    #pragma unroll 1
    for (; sb + 2 <= nfull; sb += 2) {
        STAGE(bufB, sb + 1);             // stage next SB while computing current
        CONS_FULL(bufA);
        WAIT0;
        STAGE(bufA, sb + 2);
        CONS_FULL(bufB);
        WAIT0;
    }
    if (sb < nfull) {                    // odd nfull: one more full SB in A
        STAGE(bufB, sb + 1);
        CONS_FULL(bufA);
        WAIT0;
        CONS_TAIL(bufB);
    } else {                             // even nfull: tail SB already in A
        CONS_TAIL(bufA);
    }

    // extract alpha[2*tl] and alpha[2*tl-1]  (log2 domain via p, el)
    int idx = 2 * tl;
    int lanehi = idx >> 2, rhi = idx & 3;
    int lanelo = (idx - 1) >> 2, rlo = (idx - 1) & 3;
    float q0 = __shfl(p0, lanehi, 64), q1 = __shfl(p1, lanehi, 64);
    float q2 = __shfl(p2, lanehi, 64), q3 = __shfl(p3, lanehi, 64);
    int   eh = __shfl(el, lanehi, 64);
    float ph = (rhi == 0) ? q0 : (rhi == 1) ? q1 : (rhi == 2) ? q2 : q3;
    float g0 = __shfl(p0, lanelo, 64), g1 = __shfl(p1, lanelo, 64);
    float g2 = __shfl(p2, lanelo, 64), g3 = __shfl(p3, lanelo, 64);
    int   eo = __shfl(el, lanelo, 64);
    float pl = (rlo == 0) ? g0 : (rlo == 1) ? g1 : (rlo == 2) ? g2 : g3;
    float vhi = (ph > 0.0f) ? __builtin_amdgcn_logf(ph) + (float)eh : -3.0e9f;
    float vlo = (pl > 0.0f) ? __builtin_amdgcn_logf(pl) + (float)eo : -3.0e9f;
    float m = fmaxf(vhi, vlo);
    float d = fminf(vhi, vlo) - m;
    float ll2 = m + __builtin_amdgcn_logf(1.0f + __builtin_amdgcn_exp2f(d));
    float nll = -ll2 * LN2;
    if (!(nll < 1e9f)) nll = 0.0f;      // zero_infinity (NaN-safe)

    int last = 0;
    if (l == 0) {
        nlls[b] = nll;
        __threadfence();
        unsigned old = __hip_atomic_fetch_add(cnt, 1u, __ATOMIC_ACQ_REL,
                                              __HIP_MEMORY_SCOPE_AGENT);
        last = (old == B_DIM - 1) ? 1 : 0;
    }
    last = __shfl(last, 0, 64);
    if (last) {
        // deterministic final combine (partials written by K1, stream-ordered)
        float ps = 0.0f;
        for (int i = l; i < NB1; i += 64) ps += partials[i];
        for (int off = 32; off; off >>= 1) ps += __shfl_down(ps, off, 64);
        float cs = 0.0f;
        if (l < B_DIM) cs = nlls[l] / (float)tlen[l];
        for (int off = 32; off; off >>= 1) cs += __shfl_down(cs, off, 64);
        if (l == 0) {
            float smooth = -ps / (float)((long long)T_DIM * B_DIM * V_DIM);
            float ctc = cs / (float)B_DIM;
            out[0] = 0.9f * ctc + 0.1f * smooth;
        }
    }
}

extern "C" void kernel_launch(void* const* d_in, const int* in_sizes, int n_in,
                              void* d_out, int out_size, void* d_ws, size_t ws_size,
                              hipStream_t stream) {
    const float* lp  = (const float*)d_in[0];
    const int* tgt   = (const int*)d_in[1];
    const int* ilen  = (const int*)d_in[2];
    const int* tlen  = (const int*)d_in[3];
    float* out = (float*)d_out;
    float* ws  = (float*)d_ws;
    hipMemsetAsync(d_ws, 0, 4, stream);
    ctc_prep<<<NB1, 256, 0, stream>>>(lp, tgt, ws);
    ctc_rec<<<B_DIM, 64, 0, stream>>>(tgt, ilen, tlen, ws, out);
}

// Round 15
// 72.197 us; speedup vs baseline: 1.2617x; 1.0523x over previous
//
#include <hip/hip_runtime.h>
#include <hip/hip_bf16.h>

#define T_DIM 800
#define B_DIM 32
#define V_DIM 1024
#define S_DIM 100
#define L2E  1.4426950408889634f
#define LN2  0.6931471805599453f

#define NB1  1600                /* K1 blocks: 16 rows each */
#define EOFF 4096                /* E starts at ws + EOFF floats (16 KB) */
#define EROW 128                 /* padded E row: 104 used slots (512 B) */
#define BROWS 801                /* per-batch row stride (row 800 = overrun pad) */

// ws layout (32-bit slots):
// [0]                  : uint counter (zeroed by ctc_prep block 0 each call)
// [1 .. 1+NB1)         : float partial sums (smoothing reduction)
// [1+NB1 .. 1+NB1+32)  : float per-batch nll
// [EOFF ..)            : E[32][801][128] emission matrix (13.1 MB)

__device__ __forceinline__ float dpp_shr1_f(float x) {
    return __int_as_float(__builtin_amdgcn_update_dpp(
        0, __float_as_int(x), 0x138, 0xF, 0xF, false));
}
__device__ __forceinline__ int dpp_shr1_i(int x) {
    return __builtin_amdgcn_update_dpp(0, x, 0x138, 0xF, 0xF, false);
}
__device__ __forceinline__ float rl50(float x) {
    return __int_as_float(__builtin_amdgcn_readlane(__float_as_int(x), 50));
}
__device__ __forceinline__ void gl16(const float* g, float* lds_dst) {
    __builtin_amdgcn_global_load_lds(
        (const __attribute__((address_space(1))) unsigned int*)g,
        (__attribute__((address_space(3))) unsigned int*)lds_dst,
        16, 0, 0);
}

// ========== K1: fused smoothing-reduction + E build (wave-independent) ==========
// Block owns 16 rows; wave w owns rows t0+4w .. t0+4w+3 with a private
// double-buffered LDS row. No inter-wave sync in the loop (DS ops within a
// wave are ordered; compiler inserts lgkmcnt for the cross-lane LDS gather).
extern "C" __global__ void __launch_bounds__(256)
ctc_prep(const float* __restrict__ lp,
         const int* __restrict__ tgt,
         float* __restrict__ ws)
{
    __shared__ float rb[4][2][V_DIM];   // 32 KB: per-wave double buffer
    __shared__ float red[4];
    float* E = ws + EOFF;
    float* partials = ws + 1;
    const int bid = blockIdx.x;
    const int tid = threadIdx.x;
    const int w = tid >> 6, j = tid & 63;
    const int b  = bid / 50;            // 50 blocks per batch
    const int t0 = (bid - b * 50) * 16 + w * 4;
    const int* tg = tgt + b * S_DIM;

    if (bid == 0 && tid == 0) ((unsigned int*)ws)[0] = 0;   // replaces memset

    // per-lane gather columns: lane j<=49 -> labels 2j,2j+1; lane 50 -> blank
    int c1 = 0, c2 = 0;
    if (j <= 49) { int2 t2 = ((const int2*)tg)[j]; c1 = t2.x; c2 = t2.y; }

    float s = 0.0f;
    #pragma unroll
    for (int i = 0; i < 4; ++i) {
        const int t = t0 + i;
        const float4* src = (const float4*)(lp + ((size_t)t * B_DIM + b) * V_DIM);
        float4 va = src[j], vb = src[j + 64], vc = src[j + 128], vd = src[j + 192];
        s += ((va.x + va.y) + (va.z + va.w)) + ((vb.x + vb.y) + (vb.z + vb.w))
           + ((vc.x + vc.y) + (vc.z + vc.w)) + ((vd.x + vd.y) + (vd.z + vd.w));
        float* rw = rb[w][i & 1];
        ((float4*)rw)[j] = va; ((float4*)rw)[j + 64] = vb;
        ((float4*)rw)[j + 128] = vc; ((float4*)rw)[j + 192] = vd;
        float a, c;
        if (j <= 49)      { a = __builtin_amdgcn_exp2f(rw[c1] * L2E);
                            c = __builtin_amdgcn_exp2f(rw[c2] * L2E); }
        else if (j == 50) { float ebv = __builtin_amdgcn_exp2f(rw[0] * L2E);
                            a = ebv; c = ebv; }
        else              { a = 0.0f; c = 0.0f; }
        ((float2*)(E + ((size_t)b * BROWS + t) * EROW))[j] = make_float2(a, c);
    }
    for (int off = 32; off; off >>= 1) s += __shfl_down(s, off, 64);
    if (j == 0) red[w] = s;
    __syncthreads();
    if (tid == 0) partials[bid] = (red[0] + red[1]) + (red[2] + red[3]);
}

// ========== K2: recursion — global_load_lds double-buffer, vmcnt(0) only ==========
// (byte-identical to R14's validated kernel)
extern "C" __global__ void __launch_bounds__(64)
ctc_rec(const int* __restrict__ tgt,
        const int* __restrict__ ilen,
        const int* __restrict__ tlen,
        float* __restrict__ ws,
        float* __restrict__ out)
{
    __shared__ float bufA[32 * EROW];   // 16 KB
    __shared__ float bufB[32 * EROW];   // 16 KB
    unsigned int* cnt = (unsigned int*)ws;
    float* partials = ws + 1;
    float* nlls = ws + 1 + NB1;
    const int b = blockIdx.x;
    const int l = threadIdx.x;
    const float* E = ws + EOFF + (size_t)b * BROWS * EROW;
    const int* tg = tgt + b * S_DIM;
    const int len = ilen[b];
    const int tl  = tlen[b];
    const int steps = len - 1;          // t = 1..len-1 ; len in [400,800]

    float cs1f = 0, cs3f = 0;
    if (l <= 49) {
        int v1 = tg[2 * l];
        int vp = (l >= 1) ? tg[2 * l - 1] : -1;
        cs1f = (v1 != vp) ? 1.0f : 0.0f;
        int v3 = tg[2 * l + 1];
        cs3f = (v3 != v1) ? 1.0f : 0.0f;
    }

    float p0 = 0, p1 = 0, p2 = 0, p3 = 0;
    float qv = 0, sff = 0, sfg = 0;
    int   el = 0, eLp = 0;
    {
        float2 q0 = ((const float2*)E)[l];
        float eb0 = rl50(q0.x);
        p0 = (l == 0) ? eb0  : 0.0f;
        p1 = (l == 0) ? q0.x : 0.0f;
    }

    float2 ga0, ga1, ga2, ga3, gb0, gb1, gb2, gb3;

#define STAGE(BUF, SB) do { \
    const int tb_ = 1 + 32 * (SB); \
    _Pragma("unroll") \
    for (int g_ = 0; g_ < 16; ++g_) { \
        gl16(E + (size_t)(tb_ + 2 * g_) * EROW + 4 * l, &BUF[g_ * 256]); \
    } \
} while (0)

#define WAIT0 do { \
    asm volatile("s_waitcnt vmcnt(0)" ::: "memory"); \
    __builtin_amdgcn_sched_barrier(0); \
} while (0)

#define PREF_(BUF, G, R0, R1, R2, R3) do { \
    const float2* bp_ = (const float2*)(BUF); \
    R0 = bp_[(4 * (G) + 0) * 64 + l]; \
    R1 = bp_[(4 * (G) + 1) * 64 + l]; \
    R2 = bp_[(4 * (G) + 2) * 64 + l]; \
    R3 = bp_[(4 * (G) + 3) * 64 + l]; \
} while (0)

#define BD do { \
    float mz_ = fmaxf(fmaxf(p0, p1), fmaxf(p2, p3)); \
    int dead_ = (mz_ == 0.0f) ? 1 : 0; \
    int er_ = (int)((__float_as_uint(mz_) >> 23) & 255u); \
    unsigned fld_ = dead_ ? 127u : (unsigned)(254 - er_); \
    float sc_ = __uint_as_float(fld_ << 23); \
    p0 *= sc_; p1 *= sc_; p2 *= sc_; p3 *= sc_; \
    el += dead_ ? 0 : (er_ - 127); \
    int e1s_ = dpp_shr1_i(el); \
    int elA_ = dead_ ? e1s_ : el; \
    int e2s_ = dpp_shr1_i(elA_); \
    int elB_ = dead_ ? e2s_ : el; \
    int e3s_ = dpp_shr1_i(elB_); \
    int d1_ = e3s_ - elB_; d1_ = d1_ < -120 ? -120 : (d1_ > 120 ? 120 : d1_); \
    int d2_ = eLp  - elB_; d2_ = d2_ < -120 ? -120 : (d2_ > 120 ? 120 : d2_); \
    sfg = (l == 0) ? 0.0f : __uint_as_float((unsigned)(d1_ + 127) << 23); \
    sff = (l == 0) ? 0.0f : __uint_as_float((unsigned)(d2_ + 127) << 23); \
    el = elB_; eLp = e3s_; \
} while (0)

#define ST(SF, Q, EBS) do { \
    float h3_ = qv * (SF); \
    float vown_ = fmaf(cs3f, p1, p2 + p3); \
    float n3_ = vown_ * (Q).y; \
    float n0_ = (p0 + h3_) * (EBS); \
    float n1_ = fmaf(cs1f, h3_, p0 + p1) * (Q).x; \
    float n2_ = (p1 + p2) * (EBS); \
    qv = dpp_shr1_f(n3_); \
    p0 = n0_; p1 = n1_; p2 = n2_; p3 = n3_; \
} while (0)

#define GRP_(R0, R1, R2, R3) do { \
    BD; \
    ST(sff, R0, rl50(R0.x)); \
    ST(sfg, R1, rl50(R1.x)); \
    ST(sfg, R2, rl50(R2.x)); \
    ST(sfg, R3, rl50(R3.x)); \
} while (0)

#define GRPT_(R0, R1, R2, R3, BASE) do { \
    if ((BASE) < nst) { \
        BD; \
        ST(sff, R0, rl50(R0.x)); \
        if ((BASE) + 1 < nst) ST(sfg, R1, rl50(R1.x)); \
        if ((BASE) + 2 < nst) ST(sfg, R2, rl50(R2.x)); \
        if ((BASE) + 3 < nst) ST(sfg, R3, rl50(R3.x)); \
    } \
} while (0)

#define CONS_FULL(BUF) do { \
    PREF_(BUF, 0, ga0, ga1, ga2, ga3); \
    PREF_(BUF, 1, gb0, gb1, gb2, gb3); GRP_(ga0, ga1, ga2, ga3); \
    PREF_(BUF, 2, ga0, ga1, ga2, ga3); GRP_(gb0, gb1, gb2, gb3); \
    PREF_(BUF, 3, gb0, gb1, gb2, gb3); GRP_(ga0, ga1, ga2, ga3); \
    PREF_(BUF, 4, ga0, ga1, ga2, ga3); GRP_(gb0, gb1, gb2, gb3); \
    PREF_(BUF, 5, gb0, gb1, gb2, gb3); GRP_(ga0, ga1, ga2, ga3); \
    PREF_(BUF, 6, ga0, ga1, ga2, ga3); GRP_(gb0, gb1, gb2, gb3); \
    PREF_(BUF, 7, gb0, gb1, gb2, gb3); GRP_(ga0, ga1, ga2, ga3); \
    GRP_(gb0, gb1, gb2, gb3); \
} while (0)

#define CONS_TAIL(BUF) do { \
    PREF_(BUF, 0, ga0, ga1, ga2, ga3); \
    PREF_(BUF, 1, gb0, gb1, gb2, gb3); GRPT_(ga0, ga1, ga2, ga3, 0); \
    PREF_(BUF, 2, ga0, ga1, ga2, ga3); GRPT_(gb0, gb1, gb2, gb3, 4); \
    PREF_(BUF, 3, gb0, gb1, gb2, gb3); GRPT_(ga0, ga1, ga2, ga3, 8); \
    PREF_(BUF, 4, ga0, ga1, ga2, ga3); GRPT_(gb0, gb1, gb2, gb3, 12); \
    PREF_(BUF, 5, gb0, gb1, gb2, gb3); GRPT_(ga0, ga1, ga2, ga3, 16); \
    PREF_(BUF, 6, ga0, ga1, ga2, ga3); GRPT_(gb0, gb1, gb2, gb3, 20); \
    PREF_(BUF, 7, gb0, gb1, gb2, gb3); GRPT_(ga0, ga1, ga2, ga3, 24); \
    GRPT_(gb0, gb1, gb2, gb3, 28); \
} while (0)

    const int nfull = steps >> 5;       // full 32-step superblocks (>= 12)
    const int nst   = steps & 31;       // tail steps (0..31)

    STAGE(bufA, 0);
    WAIT0;
    int sb = 0;
    #pragma unroll 1
    for (; sb + 2 <= nfull; sb += 2) {
        STAGE(bufB, sb + 1);
        CONS_FULL(bufA);
        WAIT0;
        STAGE(bufA, sb + 2);
        CONS_FULL(bufB);
        WAIT0;
    }
    if (sb < nfull) {
        STAGE(bufB, sb + 1);
        CONS_FULL(bufA);
        WAIT0;
        CONS_TAIL(bufB);
    } else {
        CONS_TAIL(bufA);
    }

    // extract alpha[2*tl] and alpha[2*tl-1]  (log2 domain via p, el)
    int idx = 2 * tl;
    int lanehi = idx >> 2, rhi = idx & 3;
    int lanelo = (idx - 1) >> 2, rlo = (idx - 1) & 3;
    float q0 = __shfl(p0, lanehi, 64), q1 = __shfl(p1, lanehi, 64);
    float q2 = __shfl(p2, lanehi, 64), q3 = __shfl(p3, lanehi, 64);
    int   eh = __shfl(el, lanehi, 64);
    float ph = (rhi == 0) ? q0 : (rhi == 1) ? q1 : (rhi == 2) ? q2 : q3;
    float g0 = __shfl(p0, lanelo, 64), g1 = __shfl(p1, lanelo, 64);
    float g2 = __shfl(p2, lanelo, 64), g3 = __shfl(p3, lanelo, 64);
    int   eo = __shfl(el, lanelo, 64);
    float pl = (rlo == 0) ? g0 : (rlo == 1) ? g1 : (rlo == 2) ? g2 : g3;
    float vhi = (ph > 0.0f) ? __builtin_amdgcn_logf(ph) + (float)eh : -3.0e9f;
    float vlo = (pl > 0.0f) ? __builtin_amdgcn_logf(pl) + (float)eo : -3.0e9f;
    float m = fmaxf(vhi, vlo);
    float d = fminf(vhi, vlo) - m;
    float ll2 = m + __builtin_amdgcn_logf(1.0f + __builtin_amdgcn_exp2f(d));
    float nll = -ll2 * LN2;
    if (!(nll < 1e9f)) nll = 0.0f;      // zero_infinity (NaN-safe)

    int last = 0;
    if (l == 0) {
        nlls[b] = nll;
        __threadfence();
        unsigned old = __hip_atomic_fetch_add(cnt, 1u, __ATOMIC_ACQ_REL,
                                              __HIP_MEMORY_SCOPE_AGENT);
        last = (old == B_DIM - 1) ? 1 : 0;
    }
    last = __shfl(last, 0, 64);
    if (last) {
        float ps = 0.0f;
        for (int i = l; i < NB1; i += 64) ps += partials[i];
        for (int off = 32; off; off >>= 1) ps += __shfl_down(ps, off, 64);
        float cs = 0.0f;
        if (l < B_DIM) cs = nlls[l] / (float)tlen[l];
        for (int off = 32; off; off >>= 1) cs += __shfl_down(cs, off, 64);
        if (l == 0) {
            float smooth = -ps / (float)((long long)T_DIM * B_DIM * V_DIM);
            float ctc = cs / (float)B_DIM;
            out[0] = 0.9f * ctc + 0.1f * smooth;
        }
    }
}

extern "C" void kernel_launch(void* const* d_in, const int* in_sizes, int n_in,
                              void* d_out, int out_size, void* d_ws, size_t ws_size,
                              hipStream_t stream) {
    const float* lp  = (const float*)d_in[0];
    const int* tgt   = (const int*)d_in[1];
    const int* ilen  = (const int*)d_in[2];
    const int* tlen  = (const int*)d_in[3];
    float* out = (float*)d_out;
    float* ws  = (float*)d_ws;
    ctc_prep<<<NB1, 256, 0, stream>>>(lp, tgt, ws);
    ctc_rec<<<B_DIM, 64, 0, stream>>>(tgt, ilen, tlen, ws, out);
}

// Round 16
// 63.401 us; speedup vs baseline: 1.4368x; 1.1388x over previous
//
#include <hip/hip_runtime.h>
#include <hip/hip_bf16.h>

#define T_DIM 800
#define B_DIM 32
#define V_DIM 1024
#define S_DIM 100
#define L2E  1.4426950408889634f
#define LN2  0.6931471805599453f

#define NB1  1600                /* K1 blocks: 16 rows each */
#define EOFF 4096                /* E starts at ws + EOFF floats (16 KB) */
#define EROW 128                 /* padded E row: 104 used slots (512 B) */
#define BROWS 801                /* per-batch row stride (row 800 = overrun pad) */

// ws layout (32-bit slots):
// [0]                  : uint counter (zeroed by ctc_prep block 0 each call)
// [1 .. 1+NB1)         : float partial sums (smoothing reduction)
// [1+NB1 .. 1+NB1+32)  : float per-batch nll
// [EOFF ..)            : E[32][801][128] emission matrix (13.1 MB)

__device__ __forceinline__ float dpp_shr1_f(float x) {
    return __int_as_float(__builtin_amdgcn_update_dpp(
        0, __float_as_int(x), 0x138, 0xF, 0xF, false));
}
__device__ __forceinline__ int dpp_shr1_i(int x) {
    return __builtin_amdgcn_update_dpp(0, x, 0x138, 0xF, 0xF, false);
}
__device__ __forceinline__ float rl50(float x) {
    return __int_as_float(__builtin_amdgcn_readlane(__float_as_int(x), 50));
}
__device__ __forceinline__ void gl16(const float* g, float* lds_dst) {
    __builtin_amdgcn_global_load_lds(
        (const __attribute__((address_space(1))) unsigned int*)g,
        (__attribute__((address_space(3))) unsigned int*)lds_dst,
        16, 0, 0);
}

// ========== K1: fused smoothing-reduction + E build (byte-identical to R15) ==========
extern "C" __global__ void __launch_bounds__(256)
ctc_prep(const float* __restrict__ lp,
         const int* __restrict__ tgt,
         float* __restrict__ ws)
{
    __shared__ float rb[4][2][V_DIM];   // 32 KB: per-wave double buffer
    __shared__ float red[4];
    float* E = ws + EOFF;
    float* partials = ws + 1;
    const int bid = blockIdx.x;
    const int tid = threadIdx.x;
    const int w = tid >> 6, j = tid & 63;
    const int b  = bid / 50;            // 50 blocks per batch
    const int t0 = (bid - b * 50) * 16 + w * 4;
    const int* tg = tgt + b * S_DIM;

    if (bid == 0 && tid == 0) ((unsigned int*)ws)[0] = 0;   // replaces memset

    int c1 = 0, c2 = 0;
    if (j <= 49) { int2 t2 = ((const int2*)tg)[j]; c1 = t2.x; c2 = t2.y; }

    float s = 0.0f;
    #pragma unroll
    for (int i = 0; i < 4; ++i) {
        const int t = t0 + i;
        const float4* src = (const float4*)(lp + ((size_t)t * B_DIM + b) * V_DIM);
        float4 va = src[j], vb = src[j + 64], vc = src[j + 128], vd = src[j + 192];
        s += ((va.x + va.y) + (va.z + va.w)) + ((vb.x + vb.y) + (vb.z + vb.w))
           + ((vc.x + vc.y) + (vc.z + vc.w)) + ((vd.x + vd.y) + (vd.z + vd.w));
        float* rw = rb[w][i & 1];
        ((float4*)rw)[j] = va; ((float4*)rw)[j + 64] = vb;
        ((float4*)rw)[j + 128] = vc; ((float4*)rw)[j + 192] = vd;
        float a, c;
        if (j <= 49)      { a = __builtin_amdgcn_exp2f(rw[c1] * L2E);
                            c = __builtin_amdgcn_exp2f(rw[c2] * L2E); }
        else if (j == 50) { float ebv = __builtin_amdgcn_exp2f(rw[0] * L2E);
                            a = ebv; c = ebv; }
        else              { a = 0.0f; c = 0.0f; }
        ((float2*)(E + ((size_t)b * BROWS + t) * EROW))[j] = make_float2(a, c);
    }
    for (int off = 32; off; off >>= 1) s += __shfl_down(s, off, 64);
    if (j == 0) red[w] = s;
    __syncthreads();
    if (tid == 0) partials[bid] = (red[0] + red[1]) + (red[2] + red[3]);
}

// ========== K2: recursion — producer/consumer wave split ==========
// Wave 1 stages superblocks via global_load_lds (+vmcnt(0)+s_barrier); wave 0
// runs the recursion with NO vmem ops in its loop, so the conservative
// LDS-DMA-vs-ds_read vmcnt waits (R14/R15 serializer) can't appear in its
// stream. Ordering purely via matched s_barrier counts. Math = validated
// R6..R15 protocol, byte-identical.
extern "C" __global__ void __launch_bounds__(128)
ctc_rec(const int* __restrict__ tgt,
        const int* __restrict__ ilen,
        const int* __restrict__ tlen,
        float* __restrict__ ws,
        float* __restrict__ out)
{
    __shared__ float bufA[32 * EROW];   // 16 KB
    __shared__ float bufB[32 * EROW];   // 16 KB
    unsigned int* cnt = (unsigned int*)ws;
    float* partials = ws + 1;
    float* nlls = ws + 1 + NB1;
    const int b = blockIdx.x;
    const int tid = threadIdx.x;
    const int wav = tid >> 6;
    const int l = tid & 63;
    const float* E = ws + EOFF + (size_t)b * BROWS * EROW;
    const int* tg = tgt + b * S_DIM;
    const int len = ilen[b];
    const int tl  = tlen[b];
    const int steps = len - 1;          // t = 1..len-1 ; len in [400,800]
    const int nfull = steps >> 5;
    const int nst   = steps & 31;
    const int N     = nfull + (nst ? 1 : 0);

#define STAGE_P(BUFP, SB) do { \
    const int tb_ = 1 + 32 * (SB); \
    float* bp_ = (BUFP); \
    _Pragma("unroll") \
    for (int g_ = 0; g_ < 16; ++g_) { \
        gl16(E + (size_t)(tb_ + 2 * g_) * EROW + 4 * l, bp_ + g_ * 256); \
    } \
} while (0)

#define WAIT0 do { \
    asm volatile("s_waitcnt vmcnt(0)" ::: "memory"); \
    __builtin_amdgcn_sched_barrier(0); \
} while (0)

    if (wav == 1) {
        // ---------------- stager wave ----------------
        STAGE_P(bufA, 0); WAIT0;
        __builtin_amdgcn_s_barrier();                // bar#0: buf(0) ready
        #pragma unroll 1
        for (int k = 1; k < N; ++k) {
            STAGE_P((k & 1) ? bufB : bufA, k); WAIT0;
            __builtin_amdgcn_s_barrier();            // bar#k: buf(k) ready, buf(k-1) consumed
        }
        return;                                       // exactly N barriers
    }

    // ---------------- consumer wave ----------------
    float cs1f = 0, cs3f = 0;
    if (l <= 49) {
        int v1 = tg[2 * l];
        int vp = (l >= 1) ? tg[2 * l - 1] : -1;
        cs1f = (v1 != vp) ? 1.0f : 0.0f;
        int v3 = tg[2 * l + 1];
        cs3f = (v3 != v1) ? 1.0f : 0.0f;
    }

    float p0 = 0, p1 = 0, p2 = 0, p3 = 0;
    float qv = 0, sff = 0, sfg = 0;
    int   el = 0, eLp = 0;
    {
        float2 q0 = ((const float2*)E)[l];
        float eb0 = rl50(q0.x);
        p0 = (l == 0) ? eb0  : 0.0f;
        p1 = (l == 0) ? q0.x : 0.0f;
    }

    float2 ga0, ga1, ga2, ga3, gb0, gb1, gb2, gb3;

#define PREF_(BUF, G, R0, R1, R2, R3) do { \
    const float2* bp_ = (const float2*)(BUF); \
    R0 = bp_[(4 * (G) + 0) * 64 + l]; \
    R1 = bp_[(4 * (G) + 1) * 64 + l]; \
    R2 = bp_[(4 * (G) + 2) * 64 + l]; \
    R3 = bp_[(4 * (G) + 3) * 64 + l]; \
} while (0)

#define BD do { \
    float mz_ = fmaxf(fmaxf(p0, p1), fmaxf(p2, p3)); \
    int dead_ = (mz_ == 0.0f) ? 1 : 0; \
    int er_ = (int)((__float_as_uint(mz_) >> 23) & 255u); \
    unsigned fld_ = dead_ ? 127u : (unsigned)(254 - er_); \
    float sc_ = __uint_as_float(fld_ << 23); \
    p0 *= sc_; p1 *= sc_; p2 *= sc_; p3 *= sc_; \
    el += dead_ ? 0 : (er_ - 127); \
    int e1s_ = dpp_shr1_i(el); \
    int elA_ = dead_ ? e1s_ : el; \
    int e2s_ = dpp_shr1_i(elA_); \
    int elB_ = dead_ ? e2s_ : el; \
    int e3s_ = dpp_shr1_i(elB_); \
    int d1_ = e3s_ - elB_; d1_ = d1_ < -120 ? -120 : (d1_ > 120 ? 120 : d1_); \
    int d2_ = eLp  - elB_; d2_ = d2_ < -120 ? -120 : (d2_ > 120 ? 120 : d2_); \
    sfg = (l == 0) ? 0.0f : __uint_as_float((unsigned)(d1_ + 127) << 23); \
    sff = (l == 0) ? 0.0f : __uint_as_float((unsigned)(d2_ + 127) << 23); \
    el = elB_; eLp = e3s_; \
} while (0)

#define ST(SF, Q, EBS) do { \
    float h3_ = qv * (SF); \
    float vown_ = fmaf(cs3f, p1, p2 + p3); \
    float n3_ = vown_ * (Q).y; \
    float n0_ = (p0 + h3_) * (EBS); \
    float n1_ = fmaf(cs1f, h3_, p0 + p1) * (Q).x; \
    float n2_ = (p1 + p2) * (EBS); \
    qv = dpp_shr1_f(n3_); \
    p0 = n0_; p1 = n1_; p2 = n2_; p3 = n3_; \
} while (0)

#define GRP_(R0, R1, R2, R3) do { \
    BD; \
    ST(sff, R0, rl50(R0.x)); \
    ST(sfg, R1, rl50(R1.x)); \
    ST(sfg, R2, rl50(R2.x)); \
    ST(sfg, R3, rl50(R3.x)); \
} while (0)

#define GRPT_(R0, R1, R2, R3, BASE) do { \
    if ((BASE) < nst) { \
        BD; \
        ST(sff, R0, rl50(R0.x)); \
        if ((BASE) + 1 < nst) ST(sfg, R1, rl50(R1.x)); \
        if ((BASE) + 2 < nst) ST(sfg, R2, rl50(R2.x)); \
        if ((BASE) + 3 < nst) ST(sfg, R3, rl50(R3.x)); \
    } \
} while (0)

#define CONS_FULL(BUF) do { \
    PREF_(BUF, 0, ga0, ga1, ga2, ga3); \
    PREF_(BUF, 1, gb0, gb1, gb2, gb3); GRP_(ga0, ga1, ga2, ga3); \
    PREF_(BUF, 2, ga0, ga1, ga2, ga3); GRP_(gb0, gb1, gb2, gb3); \
    PREF_(BUF, 3, gb0, gb1, gb2, gb3); GRP_(ga0, ga1, ga2, ga3); \
    PREF_(BUF, 4, ga0, ga1, ga2, ga3); GRP_(gb0, gb1, gb2, gb3); \
    PREF_(BUF, 5, gb0, gb1, gb2, gb3); GRP_(ga0, ga1, ga2, ga3); \
    PREF_(BUF, 6, ga0, ga1, ga2, ga3); GRP_(gb0, gb1, gb2, gb3); \
    PREF_(BUF, 7, gb0, gb1, gb2, gb3); GRP_(ga0, ga1, ga2, ga3); \
    GRP_(gb0, gb1, gb2, gb3); \
} while (0)

#define CONS_TAIL(BUF) do { \
    PREF_(BUF, 0, ga0, ga1, ga2, ga3); \
    PREF_(BUF, 1, gb0, gb1, gb2, gb3); GRPT_(ga0, ga1, ga2, ga3, 0); \
    PREF_(BUF, 2, ga0, ga1, ga2, ga3); GRPT_(gb0, gb1, gb2, gb3, 4); \
    PREF_(BUF, 3, gb0, gb1, gb2, gb3); GRPT_(ga0, ga1, ga2, ga3, 8); \
    PREF_(BUF, 4, ga0, ga1, ga2, ga3); GRPT_(gb0, gb1, gb2, gb3, 12); \
    PREF_(BUF, 5, gb0, gb1, gb2, gb3); GRPT_(ga0, ga1, ga2, ga3, 16); \
    PREF_(BUF, 6, ga0, ga1, ga2, ga3); GRPT_(gb0, gb1, gb2, gb3, 20); \
    PREF_(BUF, 7, gb0, gb1, gb2, gb3); GRPT_(ga0, ga1, ga2, ga3, 24); \
    GRPT_(gb0, gb1, gb2, gb3, 28); \
} while (0)

    __builtin_amdgcn_s_barrier();                    // bar#0: buf(0) ready
    #pragma unroll 1
    for (int k = 0; k + 1 < N; ++k) {
        const float* cur = (k & 1) ? bufB : bufA;
        CONS_FULL(cur);
        __builtin_amdgcn_s_barrier();                // bar#k+1
    }
    {
        const float* cur = ((N - 1) & 1) ? bufB : bufA;
        if (nst) { CONS_TAIL(cur); } else { CONS_FULL(cur); }
    }

    // extract alpha[2*tl] and alpha[2*tl-1]  (log2 domain via p, el)
    int idx = 2 * tl;
    int lanehi = idx >> 2, rhi = idx & 3;
    int lanelo = (idx - 1) >> 2, rlo = (idx - 1) & 3;
    float q0 = __shfl(p0, lanehi, 64), q1 = __shfl(p1, lanehi, 64);
    float q2 = __shfl(p2, lanehi, 64), q3 = __shfl(p3, lanehi, 64);
    int   eh = __shfl(el, lanehi, 64);
    float ph = (rhi == 0) ? q0 : (rhi == 1) ? q1 : (rhi == 2) ? q2 : q3;
    float g0 = __shfl(p0, lanelo, 64), g1 = __shfl(p1, lanelo, 64);
    float g2 = __shfl(p2, lanelo, 64), g3 = __shfl(p3, lanelo, 64);
    int   eo = __shfl(el, lanelo, 64);
    float pl = (rlo == 0) ? g0 : (rlo == 1) ? g1 : (rlo == 2) ? g2 : g3;
    float vhi = (ph > 0.0f) ? __builtin_amdgcn_logf(ph) + (float)eh : -3.0e9f;
    float vlo = (pl > 0.0f) ? __builtin_amdgcn_logf(pl) + (float)eo : -3.0e9f;
    float m = fmaxf(vhi, vlo);
    float d = fminf(vhi, vlo) - m;
    float ll2 = m + __builtin_amdgcn_logf(1.0f + __builtin_amdgcn_exp2f(d));
    float nll = -ll2 * LN2;
    if (!(nll < 1e9f)) nll = 0.0f;      // zero_infinity (NaN-safe)

    int last = 0;
    if (l == 0) {
        nlls[b] = nll;
        __threadfence();
        unsigned old = __hip_atomic_fetch_add(cnt, 1u, __ATOMIC_ACQ_REL,
                                              __HIP_MEMORY_SCOPE_AGENT);
        last = (old == B_DIM - 1) ? 1 : 0;
    }
    last = __shfl(last, 0, 64);
    if (last) {
        float ps = 0.0f;
        for (int i = l; i < NB1; i += 64) ps += partials[i];
        for (int off = 32; off; off >>= 1) ps += __shfl_down(ps, off, 64);
        float cs = 0.0f;
        if (l < B_DIM) cs = nlls[l] / (float)tlen[l];
        for (int off = 32; off; off >>= 1) cs += __shfl_down(cs, off, 64);
        if (l == 0) {
            float smooth = -ps / (float)((long long)T_DIM * B_DIM * V_DIM);
            float ctc = cs / (float)B_DIM;
            out[0] = 0.9f * ctc + 0.1f * smooth;
        }
    }
}

extern "C" void kernel_launch(void* const* d_in, const int* in_sizes, int n_in,
                              void* d_out, int out_size, void* d_ws, size_t ws_size,
                              hipStream_t stream) {
    const float* lp  = (const float*)d_in[0];
    const int* tgt   = (const int*)d_in[1];
    const int* ilen  = (const int*)d_in[2];
    const int* tlen  = (const int*)d_in[3];
    float* out = (float*)d_out;
    float* ws  = (float*)d_ws;
    ctc_prep<<<NB1, 256, 0, stream>>>(lp, tgt, ws);
    ctc_rec<<<B_DIM, 128, 0, stream>>>(tgt, ilen, tlen, ws, out);
}